// Round 1
// baseline (259.934 us; speedup 1.0000x reference)
//
#include <hip/hip_runtime.h>
#include <hip/hip_bf16.h>

typedef __bf16 bf16_t;
typedef __bf16 bf16x8 __attribute__((ext_vector_type(8)));
typedef float f32x4 __attribute__((ext_vector_type(4)));

#define NB 16
#define HW 56
#define DIM 192
#define N3 576
#define WS7 7
#define HEADS 6
#define HD 32
#define NTOK 49

// ---------------- prep: roll(-3,-3) + fp32->bf16 of x ----------------
__global__ __launch_bounds__(256) void prep_x_kernel(const float* __restrict__ x,
                                                     bf16_t* __restrict__ xb) {
    int idx = blockIdx.x * 256 + threadIdx.x;          // over NB*HW*HW*(DIM/8)
    const int total = NB * HW * HW * (DIM / 8);
    if (idx >= total) return;
    int c8 = idx % (DIM / 8);
    int p  = idx / (DIM / 8);
    int xx = p % HW;
    int yy = (p / HW) % HW;
    int bb = p / (HW * HW);
    int ys = yy + 3; if (ys >= HW) ys -= HW;           // roll(-3): out[y] = in[(y+3)%56]
    int xs = xx + 3; if (xs >= HW) xs -= HW;
    const float* src = x + ((size_t)(bb * HW + ys) * HW + xs) * DIM + c8 * 8;
    float4 a0 = *reinterpret_cast<const float4*>(src);
    float4 a1 = *reinterpret_cast<const float4*>(src + 4);
    bf16x8 o;
    o[0] = (bf16_t)a0.x; o[1] = (bf16_t)a0.y; o[2] = (bf16_t)a0.z; o[3] = (bf16_t)a0.w;
    o[4] = (bf16_t)a1.x; o[5] = (bf16_t)a1.y; o[6] = (bf16_t)a1.z; o[7] = (bf16_t)a1.w;
    *reinterpret_cast<bf16x8*>(xb + (size_t)idx * 8) = o;
}

// ---------------- prep: transpose+cast weights to [n][k] bf16 ----------------
__global__ __launch_bounds__(256) void prep_w_kernel(const float* __restrict__ wqkv,
                                                     const float* __restrict__ wout,
                                                     bf16_t* __restrict__ wqkvt,
                                                     bf16_t* __restrict__ woutt) {
    int idx = blockIdx.x * 256 + threadIdx.x;
    if (idx < N3 * DIM) {                      // wqkvt[n][k] = wqkv[k][n]
        int k = idx % DIM, n = idx / DIM;
        wqkvt[idx] = (bf16_t)wqkv[(size_t)k * N3 + n];
    } else {
        int j = idx - N3 * DIM;
        if (j < DIM * DIM) {                   // woutt[n][k] = wout[k][n]
            int k = j % DIM, n = j / DIM;
            woutt[j] = (bf16_t)wout[(size_t)k * DIM + n];
        }
    }
}

// ---------------- K1: QKV GEMM  C[50176,576] = xb[50176,192] @ wqkvt^T ----------------
__global__ __launch_bounds__(256) void qkv_gemm_kernel(const bf16_t* __restrict__ xb,
                                                       const bf16_t* __restrict__ wt,
                                                       bf16_t* __restrict__ qkv) {
    int mblk = blockIdx.x, nblk = blockIdx.y;
    int wave = threadIdx.x >> 6, lane = threadIdx.x & 63;
    int lo = lane & 15, hi = lane >> 4;
    const bf16_t* arow = xb + (size_t)(mblk * 64 + wave * 16 + lo) * DIM + hi * 8;
    const bf16_t* bcol = wt + (size_t)(nblk * 64 + lo) * DIM + hi * 8;
    f32x4 acc[4];
#pragma unroll
    for (int ct = 0; ct < 4; ct++) acc[ct] = (f32x4){0.f, 0.f, 0.f, 0.f};
#pragma unroll
    for (int ks = 0; ks < 6; ks++) {
        bf16x8 a = *reinterpret_cast<const bf16x8*>(arow + ks * 32);
#pragma unroll
        for (int ct = 0; ct < 4; ct++) {
            bf16x8 b = *reinterpret_cast<const bf16x8*>(bcol + (size_t)ct * 16 * DIM + ks * 32);
            acc[ct] = __builtin_amdgcn_mfma_f32_16x16x32_bf16(a, b, acc[ct], 0, 0, 0);
        }
    }
    size_t orow = (size_t)(mblk * 64 + wave * 16 + hi * 4);
#pragma unroll
    for (int ct = 0; ct < 4; ct++)
#pragma unroll
        for (int r = 0; r < 4; r++)
            qkv[(orow + r) * N3 + nblk * 64 + ct * 16 + lo] = (bf16_t)acc[ct][r];
}

// ---------------- K2: per-(window,head) attention ----------------
__global__ __launch_bounds__(64) void attn_kernel(const bf16_t* __restrict__ qkv,
                                                  const float* __restrict__ pe,
                                                  bf16_t* __restrict__ att) {
    const int win = blockIdx.x, h = blockIdx.y, bb = blockIdx.z;
    const int wh = win >> 3, ww = win & 7;
    const int lane = threadIdx.x;
    const int lo = lane & 15, hi = lane >> 4;

    __shared__ float pes[169];
    __shared__ bf16_t P[64][72];                 // stride 72 to break bank conflicts
    for (int i = lane; i < 169; i += 64) pes[i] = pe[i];
    __syncthreads();

    auto tokoff = [&](int t) -> size_t {         // t < 49; offset of (token t, channel h*32)
        int ti = t / 7, tj = t % 7;
        return ((size_t)(bb * HW + wh * WS7 + ti) * HW + ww * WS7 + tj) * N3 + h * HD;
    };

    // Q (A-frag) and K (B-frag) loads: both patterns read 8 contiguous d at token (l&15)
    bf16x8 qf[4], kf[4];
#pragma unroll
    for (int t4 = 0; t4 < 4; t4++) {
        int t = t4 * 16 + lo;
        if (t < NTOK) {
            size_t off = tokoff(t) + hi * 8;
            qf[t4] = *reinterpret_cast<const bf16x8*>(qkv + off);          // q: +0
            kf[t4] = *reinterpret_cast<const bf16x8*>(qkv + off + DIM);    // k: +192
        } else {
#pragma unroll
            for (int j = 0; j < 8; j++) { qf[t4][j] = (bf16_t)0.f; kf[t4][j] = (bf16_t)0.f; }
        }
    }

    const f32x4 zero4 = {0.f, 0.f, 0.f, 0.f};
    f32x4 s[4][4];
#pragma unroll
    for (int mt = 0; mt < 4; mt++)
#pragma unroll
        for (int ct = 0; ct < 4; ct++)
            s[mt][ct] = __builtin_amdgcn_mfma_f32_16x16x32_bf16(qf[mt], kf[ct], zero4, 0, 0, 0);

    // bias + shift masks + softmax (rows live in 16-lane groups: row=(l>>4)*4+r, col=ct*16+(l&15))
    const float scale = 0.17677669529663687f;
    const bool maskrow = (wh == 7), maskcol = (ww == 7);
    float rinv[4][4];
#pragma unroll
    for (int mt = 0; mt < 4; mt++) {
#pragma unroll
        for (int r = 0; r < 4; r++) {
            int ti = mt * 16 + hi * 4 + r;
            int yi = ti / 7, xi = ti % 7;
            float vals[4];
            float mx = -3e38f;
#pragma unroll
            for (int ct = 0; ct < 4; ct++) {
                int tj = ct * 16 + lo;
                float v = -1e30f;
                if (ti < NTOK && tj < NTOK) {
                    int yj = tj / 7, xj = tj % 7;
                    v = s[mt][ct][r] * scale + pes[(yj - yi + 6) * 13 + (xj - xi + 6)];
                    if (maskrow && ((yi >= 4) != (yj >= 4))) v = -1e30f;
                    if (maskcol && ((xi >= 4) != (xj >= 4))) v = -1e30f;
                }
                vals[ct] = v;
                mx = fmaxf(mx, v);
            }
#pragma unroll
            for (int off = 1; off < 16; off <<= 1) mx = fmaxf(mx, __shfl_xor(mx, off));
            float sum = 0.f;
#pragma unroll
            for (int ct = 0; ct < 4; ct++) {
                float p = __expf(vals[ct] - mx);
                sum += p;
                P[ti][ct * 16 + lo] = (bf16_t)p;
            }
#pragma unroll
            for (int off = 1; off < 16; off <<= 1) sum += __shfl_xor(sum, off);
            rinv[mt][r] = 1.f / sum;
        }
    }
    __syncthreads();

    // O = P @ V  (K = 64 padded tokens, 2 MFMA K-steps; N = 32 = 2 col-tiles)
    f32x4 o[4][2];
#pragma unroll
    for (int mt = 0; mt < 4; mt++)
#pragma unroll
        for (int c2 = 0; c2 < 2; c2++) o[mt][c2] = zero4;

#pragma unroll
    for (int ks = 0; ks < 2; ks++) {
        bf16x8 vb[2];
#pragma unroll
        for (int c2 = 0; c2 < 2; c2++) {
#pragma unroll
            for (int j = 0; j < 8; j++) {
                int tv = ks * 32 + hi * 8 + j;
                vb[c2][j] = (tv < NTOK) ? qkv[tokoff(tv) + 2 * DIM + c2 * 16 + lo]
                                        : (bf16_t)0.f;   // v: +384
            }
        }
#pragma unroll
        for (int mt = 0; mt < 4; mt++) {
            bf16x8 pa = *reinterpret_cast<const bf16x8*>(&P[mt * 16 + lo][ks * 32 + hi * 8]);
#pragma unroll
            for (int c2 = 0; c2 < 2; c2++)
                o[mt][c2] = __builtin_amdgcn_mfma_f32_16x16x32_bf16(pa, vb[c2], o[mt][c2], 0, 0, 0);
        }
    }

    // write normalized O to att[b][y][x][h*32 + d]
#pragma unroll
    for (int mt = 0; mt < 4; mt++) {
#pragma unroll
        for (int r = 0; r < 4; r++) {
            int ti = mt * 16 + hi * 4 + r;
            if (ti < NTOK) {
                int y = wh * WS7 + ti / 7, x = ww * WS7 + ti % 7;
                size_t aoff = ((size_t)(bb * HW + y) * HW + x) * DIM + h * HD;
#pragma unroll
                for (int c2 = 0; c2 < 2; c2++)
                    att[aoff + c2 * 16 + lo] = (bf16_t)(o[mt][c2][r] * rinv[mt][r]);
            }
        }
    }
}

// ---------------- K3: out GEMM + bias + roll(+3,+3) ----------------
__global__ __launch_bounds__(256) void out_gemm_kernel(const bf16_t* __restrict__ att,
                                                       const bf16_t* __restrict__ wt,
                                                       const float* __restrict__ bias,
                                                       float* __restrict__ out) {
    int mblk = blockIdx.x, nblk = blockIdx.y;
    int wave = threadIdx.x >> 6, lane = threadIdx.x & 63;
    int lo = lane & 15, hi = lane >> 4;
    const bf16_t* arow = att + (size_t)(mblk * 64 + wave * 16 + lo) * DIM + hi * 8;
    const bf16_t* bcol = wt + (size_t)(nblk * 64 + lo) * DIM + hi * 8;
    f32x4 acc[4];
#pragma unroll
    for (int ct = 0; ct < 4; ct++) acc[ct] = (f32x4){0.f, 0.f, 0.f, 0.f};
#pragma unroll
    for (int ks = 0; ks < 6; ks++) {
        bf16x8 a = *reinterpret_cast<const bf16x8*>(arow + ks * 32);
#pragma unroll
        for (int ct = 0; ct < 4; ct++) {
            bf16x8 b = *reinterpret_cast<const bf16x8*>(bcol + (size_t)ct * 16 * DIM + ks * 32);
            acc[ct] = __builtin_amdgcn_mfma_f32_16x16x32_bf16(a, b, acc[ct], 0, 0, 0);
        }
    }
#pragma unroll
    for (int r = 0; r < 4; r++) {
        int m = mblk * 64 + wave * 16 + hi * 4 + r;
        int bb = m / (HW * HW);
        int rem = m % (HW * HW);
        int ya = rem / HW, xa = rem % HW;
        int yo = ya + 3; if (yo >= HW) yo -= HW;   // roll(+3): out[y] = res[(y-3)%56]
        int xo = xa + 3; if (xo >= HW) xo -= HW;
        size_t obase = ((size_t)(bb * HW + yo) * HW + xo) * DIM + nblk * 64;
#pragma unroll
        for (int ct = 0; ct < 4; ct++) {
            int col = ct * 16 + lo;
            out[obase + col] = acc[ct][r] + bias[nblk * 64 + col];
        }
    }
}

extern "C" void kernel_launch(void* const* d_in, const int* in_sizes, int n_in,
                              void* d_out, int out_size, void* d_ws, size_t ws_size,
                              hipStream_t stream) {
    const float* x    = (const float*)d_in[0];
    const float* wqkv = (const float*)d_in[1];
    const float* pe   = (const float*)d_in[2];
    const float* wout = (const float*)d_in[3];
    const float* bout = (const float*)d_in[4];
    float* out = (float*)d_out;

    char* ws = (char*)d_ws;
    const size_t XB_BYTES  = (size_t)NB * HW * HW * DIM * 2;   // 19,267,584
    const size_t QKV_BYTES = (size_t)NB * HW * HW * N3 * 2;    // 57,802,752
    const size_t ATT_BYTES = XB_BYTES;
    bf16_t* xb    = (bf16_t*)ws;
    bf16_t* qkv   = (bf16_t*)(ws + XB_BYTES);
    bf16_t* att   = (bf16_t*)(ws + XB_BYTES + QKV_BYTES);
    bf16_t* wqkvt = (bf16_t*)(ws + XB_BYTES + QKV_BYTES + ATT_BYTES);
    bf16_t* woutt = (bf16_t*)(ws + XB_BYTES + QKV_BYTES + ATT_BYTES + (size_t)N3 * DIM * 2);

    prep_x_kernel<<<(NB * HW * HW * (DIM / 8) + 255) / 256, 256, 0, stream>>>(x, xb);
    prep_w_kernel<<<(N3 * DIM + DIM * DIM + 255) / 256, 256, 0, stream>>>(wqkv, wout, wqkvt, woutt);
    qkv_gemm_kernel<<<dim3(784, 9), 256, 0, stream>>>(xb, wqkvt, qkv);
    attn_kernel<<<dim3(64, HEADS, NB), 64, 0, stream>>>(qkv, pe, att);
    out_gemm_kernel<<<dim3(784, 3), 256, 0, stream>>>(att, woutt, bout, out);
}

// Round 3
// 175.839 us; speedup vs baseline: 1.4783x; 1.4783x over previous
//
#include <hip/hip_runtime.h>
#include <hip/hip_bf16.h>

typedef __bf16 bf16_t;
typedef __bf16 bf16x8 __attribute__((ext_vector_type(8)));
typedef float f32x4 __attribute__((ext_vector_type(4)));
typedef unsigned int u32;

#define NB 16
#define HW 56
#define DIM 192
#define N3 576
#define WS7 7
#define HEADS 6
#define HD 32
#define NTOK 49
#define MFMA(a, b, c) __builtin_amdgcn_mfma_f32_16x16x32_bf16(a, b, c, 0, 0, 0)

__device__ __forceinline__ void gld_lds16(const bf16_t* g, bf16_t* l) {
    __builtin_amdgcn_global_load_lds((const __attribute__((address_space(1))) u32*)g,
                                     (__attribute__((address_space(3))) u32*)l, 16, 0, 0);
}

// ---------------- prep: roll(-3,-3) + fp32->bf16 of x ----------------
__global__ __launch_bounds__(256) void prep_x_kernel(const float* __restrict__ x,
                                                     bf16_t* __restrict__ xb) {
    int idx = blockIdx.x * 256 + threadIdx.x;
    const int total = NB * HW * HW * (DIM / 8);
    if (idx >= total) return;
    int c8 = idx % (DIM / 8);
    int p  = idx / (DIM / 8);
    int xx = p % HW;
    int yy = (p / HW) % HW;
    int bb = p / (HW * HW);
    int ys = yy + 3; if (ys >= HW) ys -= HW;
    int xs = xx + 3; if (xs >= HW) xs -= HW;
    const float* src = x + ((size_t)(bb * HW + ys) * HW + xs) * DIM + c8 * 8;
    float4 a0 = *reinterpret_cast<const float4*>(src);
    float4 a1 = *reinterpret_cast<const float4*>(src + 4);
    bf16x8 o;
    o[0] = (bf16_t)a0.x; o[1] = (bf16_t)a0.y; o[2] = (bf16_t)a0.z; o[3] = (bf16_t)a0.w;
    o[4] = (bf16_t)a1.x; o[5] = (bf16_t)a1.y; o[6] = (bf16_t)a1.z; o[7] = (bf16_t)a1.w;
    *reinterpret_cast<bf16x8*>(xb + (size_t)idx * 8) = o;
}

// ---------------- prep: transpose+cast weights to [n][k] bf16 ----------------
__global__ __launch_bounds__(256) void prep_w_kernel(const float* __restrict__ wqkv,
                                                     const float* __restrict__ wout,
                                                     bf16_t* __restrict__ wqkvt,
                                                     bf16_t* __restrict__ woutt) {
    int idx = blockIdx.x * 256 + threadIdx.x;
    if (idx < N3 * DIM) {
        int k = idx % DIM, n = idx / DIM;
        wqkvt[idx] = (bf16_t)wqkv[(size_t)k * N3 + n];
    } else {
        int j = idx - N3 * DIM;
        if (j < DIM * DIM) {
            int k = j % DIM, n = j / DIM;
            woutt[j] = (bf16_t)wout[(size_t)k * DIM + n];
        }
    }
}

// ---------------- K1: QKV GEMM  C[50176,576] = xb @ wqkvt^T ----------------
// 128x64 tile, B staged in LDS via global_load_lds + chunk-XOR swizzle, A in regs.
__global__ __launch_bounds__(256) void qkv_gemm2(const bf16_t* __restrict__ xb,
                                                 const bf16_t* __restrict__ wt,
                                                 bf16_t* __restrict__ qkv) {
    __shared__ alignas(16) bf16_t bsh[64 * DIM];     // 24576 B, swizzled layout
    const int mblk = blockIdx.x, nblk = blockIdx.y;
    const int wave = threadIdx.x >> 6, lane = threadIdx.x & 63;
    const int lo = lane & 15, hi = lane >> 4;

    // stage B tile (contiguous 24576 B): LDS chunk s gets global chunk s^((s/24)&7)
    const bf16_t* bt = wt + (size_t)nblk * 64 * DIM;
#pragma unroll
    for (int i = 0; i < 6; i++) {
        int s = wave * 384 + i * 64 + lane;          // 16B chunk index
        int g = s ^ ((s / 24) & 7);                  // pre-swizzled source
        gld_lds16(bt + g * 8, bsh + (wave * 384 + i * 64) * 8);
    }

    // A fragments straight to registers (12 independent 16B loads)
    bf16x8 a[2][6];
    const bf16_t* ab = xb + ((size_t)mblk * 128 + wave * 32 + lo) * DIM + hi * 8;
#pragma unroll
    for (int mt = 0; mt < 2; mt++)
#pragma unroll
        for (int ks = 0; ks < 6; ks++)
            a[mt][ks] = *reinterpret_cast<const bf16x8*>(ab + mt * 16 * DIM + ks * 32);

    f32x4 acc[2][4];
#pragma unroll
    for (int mt = 0; mt < 2; mt++)
#pragma unroll
        for (int ct = 0; ct < 4; ct++) acc[mt][ct] = (f32x4){0.f, 0.f, 0.f, 0.f};

    __syncthreads();

#pragma unroll
    for (int ks = 0; ks < 6; ks++)
#pragma unroll
        for (int ct = 0; ct < 4; ct++) {
            int r = ct * 16 + lo;
            int off = (ks * 64 + hi * 16) ^ ((r & 7) << 4);   // swizzled read
            bf16x8 b = *reinterpret_cast<const bf16x8*>((const char*)bsh + r * 384 + off);
            acc[0][ct] = MFMA(a[0][ks], b, acc[0][ct]);
            acc[1][ct] = MFMA(a[1][ks], b, acc[1][ct]);
        }

    const size_t rb = (size_t)mblk * 128 + wave * 32;
#pragma unroll
    for (int mt = 0; mt < 2; mt++)
#pragma unroll
        for (int ct = 0; ct < 4; ct++)
#pragma unroll
            for (int r = 0; r < 4; r++)
                qkv[(rb + mt * 16 + hi * 4 + r) * N3 + nblk * 64 + ct * 16 + lo] =
                    (bf16_t)acc[mt][ct][r];
}

// ---------------- K2: per-(window,head) attention ----------------
__global__ __launch_bounds__(64) void attn_kernel2(const bf16_t* __restrict__ qkv,
                                                   const float* __restrict__ pe,
                                                   bf16_t* __restrict__ att) {
    const int win = blockIdx.x, h = blockIdx.y, bb = blockIdx.z;
    const int wh = win >> 3, ww = win & 7;
    const int lane = threadIdx.x;
    const int lo = lane & 15, hi = lane >> 4;

    __shared__ float pes[169];
    __shared__ bf16_t P[64][72];                      // 144 B stride -> conflict-free b128
    __shared__ alignas(16) bf16_t VT[32][72];         // V transposed [d][token]

    for (int i = lane; i < 169; i += 64) pes[i] = pe[i];

    auto tokoff = [&](int t) -> size_t {
        int ti = t / 7, tj = t % 7;
        return ((size_t)(bb * HW + wh * WS7 + ti) * HW + ww * WS7 + tj) * N3 + h * HD;
    };

    // stage V transposed: lane t owns token t's 32 channels (64 B vector load)
    {
        const int t = lane;
        bf16x8 v[4];
        if (t < NTOK) {
            const bf16_t* vp = qkv + tokoff(t) + 2 * DIM;
#pragma unroll
            for (int c = 0; c < 4; c++) v[c] = *reinterpret_cast<const bf16x8*>(vp + c * 8);
        } else {
#pragma unroll
            for (int c = 0; c < 4; c++)
#pragma unroll
                for (int j = 0; j < 8; j++) v[c][j] = (bf16_t)0.f;
        }
#pragma unroll
        for (int c = 0; c < 4; c++)
#pragma unroll
            for (int j = 0; j < 8; j++) VT[c * 8 + j][t] = v[c][j];
    }
    __syncthreads();

    // Q (A-frag) and K (B-frag) vector loads
    bf16x8 qf[4], kf[4];
#pragma unroll
    for (int t4 = 0; t4 < 4; t4++) {
        int t = t4 * 16 + lo;
        if (t < NTOK) {
            size_t off = tokoff(t) + hi * 8;
            qf[t4] = *reinterpret_cast<const bf16x8*>(qkv + off);
            kf[t4] = *reinterpret_cast<const bf16x8*>(qkv + off + DIM);
        } else {
#pragma unroll
            for (int j = 0; j < 8; j++) { qf[t4][j] = (bf16_t)0.f; kf[t4][j] = (bf16_t)0.f; }
        }
    }

    const f32x4 zero4 = {0.f, 0.f, 0.f, 0.f};
    f32x4 s[4][4];
#pragma unroll
    for (int mt = 0; mt < 4; mt++)
#pragma unroll
        for (int ct = 0; ct < 4; ct++)
            s[mt][ct] = MFMA(qf[mt], kf[ct], zero4);

    const float scale = 0.17677669529663687f;
    const bool maskrow = (wh == 7), maskcol = (ww == 7);
    float rinv[4][4];
#pragma unroll
    for (int mt = 0; mt < 4; mt++) {
#pragma unroll
        for (int r = 0; r < 4; r++) {
            int ti = mt * 16 + hi * 4 + r;
            int yi = ti / 7, xi = ti % 7;
            float vals[4];
            float mx = -3e38f;
#pragma unroll
            for (int ct = 0; ct < 4; ct++) {
                int tj = ct * 16 + lo;
                float v = -1e30f;
                if (ti < NTOK && tj < NTOK) {
                    int yj = tj / 7, xj = tj % 7;
                    v = s[mt][ct][r] * scale + pes[(yj - yi + 6) * 13 + (xj - xi + 6)];
                    if (maskrow && ((yi >= 4) != (yj >= 4))) v = -1e30f;
                    if (maskcol && ((xi >= 4) != (xj >= 4))) v = -1e30f;
                }
                vals[ct] = v;
                mx = fmaxf(mx, v);
            }
#pragma unroll
            for (int off = 1; off < 16; off <<= 1) mx = fmaxf(mx, __shfl_xor(mx, off));
            float sum = 0.f;
#pragma unroll
            for (int ct = 0; ct < 4; ct++) {
                float p = __expf(vals[ct] - mx);
                sum += p;
                P[ti][ct * 16 + lo] = (bf16_t)p;
            }
#pragma unroll
            for (int off = 1; off < 16; off <<= 1) sum += __shfl_xor(sum, off);
            rinv[mt][r] = 1.f / sum;
        }
    }
    __syncthreads();

    // O = P @ V, V from transposed LDS (vector b128 reads, conflict-free)
    f32x4 o[4][2];
#pragma unroll
    for (int mt = 0; mt < 4; mt++)
#pragma unroll
        for (int c2 = 0; c2 < 2; c2++) o[mt][c2] = zero4;

#pragma unroll
    for (int ks = 0; ks < 2; ks++) {
        bf16x8 vb[2];
#pragma unroll
        for (int c2 = 0; c2 < 2; c2++)
            vb[c2] = *reinterpret_cast<const bf16x8*>(&VT[c2 * 16 + lo][ks * 32 + hi * 8]);
#pragma unroll
        for (int mt = 0; mt < 4; mt++) {
            bf16x8 pa = *reinterpret_cast<const bf16x8*>(&P[mt * 16 + lo][ks * 32 + hi * 8]);
#pragma unroll
            for (int c2 = 0; c2 < 2; c2++)
                o[mt][c2] = MFMA(pa, vb[c2], o[mt][c2]);
        }
    }

#pragma unroll
    for (int mt = 0; mt < 4; mt++) {
#pragma unroll
        for (int r = 0; r < 4; r++) {
            int ti = mt * 16 + hi * 4 + r;
            if (ti < NTOK) {
                int y = wh * WS7 + ti / 7, x = ww * WS7 + ti % 7;
                size_t aoff = ((size_t)(bb * HW + y) * HW + x) * DIM + h * HD;
#pragma unroll
                for (int c2 = 0; c2 < 2; c2++)
                    att[aoff + c2 * 16 + lo] = (bf16_t)(o[mt][c2][r] * rinv[mt][r]);
            }
        }
    }
}

// ---------------- K3: out GEMM + bias + roll(+3,+3) ----------------
__global__ __launch_bounds__(256) void out_gemm2(const bf16_t* __restrict__ att,
                                                 const bf16_t* __restrict__ wt,
                                                 const float* __restrict__ bias,
                                                 float* __restrict__ out) {
    __shared__ alignas(16) bf16_t bsh[64 * DIM];
    const int mblk = blockIdx.x, nblk = blockIdx.y;
    const int wave = threadIdx.x >> 6, lane = threadIdx.x & 63;
    const int lo = lane & 15, hi = lane >> 4;

    const bf16_t* bt = wt + (size_t)nblk * 64 * DIM;
#pragma unroll
    for (int i = 0; i < 6; i++) {
        int s = wave * 384 + i * 64 + lane;
        int g = s ^ ((s / 24) & 7);
        gld_lds16(bt + g * 8, bsh + (wave * 384 + i * 64) * 8);
    }

    bf16x8 a[2][6];
    const bf16_t* ab = att + ((size_t)mblk * 128 + wave * 32 + lo) * DIM + hi * 8;
#pragma unroll
    for (int mt = 0; mt < 2; mt++)
#pragma unroll
        for (int ks = 0; ks < 6; ks++)
            a[mt][ks] = *reinterpret_cast<const bf16x8*>(ab + mt * 16 * DIM + ks * 32);

    f32x4 acc[2][4];
#pragma unroll
    for (int mt = 0; mt < 2; mt++)
#pragma unroll
        for (int ct = 0; ct < 4; ct++) acc[mt][ct] = (f32x4){0.f, 0.f, 0.f, 0.f};

    __syncthreads();

#pragma unroll
    for (int ks = 0; ks < 6; ks++)
#pragma unroll
        for (int ct = 0; ct < 4; ct++) {
            int r = ct * 16 + lo;
            int off = (ks * 64 + hi * 16) ^ ((r & 7) << 4);
            bf16x8 b = *reinterpret_cast<const bf16x8*>((const char*)bsh + r * 384 + off);
            acc[0][ct] = MFMA(a[0][ks], b, acc[0][ct]);
            acc[1][ct] = MFMA(a[1][ks], b, acc[1][ct]);
        }

    const int rb = mblk * 128 + wave * 32;
#pragma unroll
    for (int mt = 0; mt < 2; mt++)
#pragma unroll
        for (int r = 0; r < 4; r++) {
            int m = rb + mt * 16 + hi * 4 + r;
            int bb = m / (HW * HW);
            int rem = m - bb * HW * HW;
            int ya = rem / HW, xa = rem - ya * HW;
            int yo = ya + 3; if (yo >= HW) yo -= HW;
            int xo = xa + 3; if (xo >= HW) xo -= HW;
            size_t ob = ((size_t)(bb * HW + yo) * HW + xo) * DIM + nblk * 64;
#pragma unroll
            for (int ct = 0; ct < 4; ct++)
                out[ob + ct * 16 + lo] = acc[mt][ct][r] + bias[nblk * 64 + ct * 16 + lo];
        }
}

extern "C" void kernel_launch(void* const* d_in, const int* in_sizes, int n_in,
                              void* d_out, int out_size, void* d_ws, size_t ws_size,
                              hipStream_t stream) {
    const float* x    = (const float*)d_in[0];
    const float* wqkv = (const float*)d_in[1];
    const float* pe   = (const float*)d_in[2];
    const float* wout = (const float*)d_in[3];
    const float* bout = (const float*)d_in[4];
    float* out = (float*)d_out;

    char* ws = (char*)d_ws;
    const size_t XB_BYTES  = (size_t)NB * HW * HW * DIM * 2;
    const size_t QKV_BYTES = (size_t)NB * HW * HW * N3 * 2;
    const size_t ATT_BYTES = XB_BYTES;
    bf16_t* xb    = (bf16_t*)ws;
    bf16_t* qkv   = (bf16_t*)(ws + XB_BYTES);
    bf16_t* att   = (bf16_t*)(ws + XB_BYTES + QKV_BYTES);
    bf16_t* wqkvt = (bf16_t*)(ws + XB_BYTES + QKV_BYTES + ATT_BYTES);
    bf16_t* woutt = (bf16_t*)(ws + XB_BYTES + QKV_BYTES + ATT_BYTES + (size_t)N3 * DIM * 2);

    prep_x_kernel<<<(NB * HW * HW * (DIM / 8) + 255) / 256, 256, 0, stream>>>(x, xb);
    prep_w_kernel<<<(N3 * DIM + DIM * DIM + 255) / 256, 256, 0, stream>>>(wqkv, wout, wqkvt, woutt);
    qkv_gemm2<<<dim3(392, 9), 256, 0, stream>>>(xb, wqkvt, qkv);
    attn_kernel2<<<dim3(64, HEADS, NB), 64, 0, stream>>>(qkv, pe, att);
    out_gemm2<<<dim3(392, 3), 256, 0, stream>>>(att, woutt, bout, out);
}